// Round 13
// baseline (284.194 us; speedup 1.0000x reference)
//
#include <hip/hip_runtime.h>
#include <hip/hip_bf16.h>

#define N_NODES   100000
#define N_EDGES   1600000
#define N_ETYPES  3
#define IN_FEATS  128
#define HEADS     4
#define OUT_FEATS 16
#define EDGE_FEATS 64
#define HD        64            // HEADS*OUT_FEATS
#define NEG_SLOPE 0.2f
#define MAXD_LDS  128           // agg fast-path max degree (Poisson(16): P(>128)~0)

#define NBUCK     800           // buckets for counting sort
#define NPB       125           // nodes per bucket (800*125 = N_NODES)
#define PBLK      400           // scatter blocks
#define EPB       4000          // edges per scatter block
#define BCAP      2560          // fixed bucket-region capacity (mean 2000, 12.5 sigma)
#define FROWS     32            // rows per feat block (100000/32 = 3125 exact)
#define NFEAT     (N_NODES / FROWS)   // 3125
#define WTROWS    80            // 64 feat cols + 4 el + 4 er + 8 zero-pad

// fused grid: [0,PBLK) scatter | PBLK service(ee) | (PBLK, PBLK+NFEAT] feat
// sc_bucket payload (int2): {src, e | ty<<21 | ld<<23}

typedef short s16x8 __attribute__((ext_vector_type(8)));
typedef float f32x4 __attribute__((ext_vector_type(4)));

__device__ __forceinline__ short f2bs(float f) {
    __hip_bfloat16 h = __float2bfloat16(f);
    return *reinterpret_cast<short*>(&h);
}

// ---------------------------------------------------------------------------
// Prep: WTb bf16 [80][128]. Rows 0..63: W^T. Rows 64..67: Wl (el cols),
// 68..71: Wr (er cols), 72..79: zero. Block 0 zeroes cnt.
// ---------------------------------------------------------------------------
__global__ __launch_bounds__(256) void wt_prep_kernel(
    const float* __restrict__ W,
    const float* __restrict__ attn_l,
    const float* __restrict__ attn_r,
    short* __restrict__ WTb, int* __restrict__ cnt)
{
    const int t = blockIdx.x * 256 + threadIdx.x;   // 0..10239
    const int n = t >> 7, k = t & 127;
    short v;
    if (n < 64) {
        v = f2bs(W[k * HD + n]);
    } else if (n < 72) {
        const int h = (n - 64) & 3;
        const float* av = (n < 68) ? attn_l : attn_r;
        float s = 0.f;
#pragma unroll
        for (int d = 0; d < OUT_FEATS; ++d)
            s += W[k * HD + h * OUT_FEATS + d] * av[h * OUT_FEATS + d];
        v = f2bs(s);
    } else {
        v = 0;
    }
    WTb[n * IN_FEATS + k] = v;
    if (blockIdx.x == 0)
        for (int j = threadIdx.x; j < NBUCK; j += 256) cnt[j] = 0;
}

// ---------------------------------------------------------------------------
// FUSED kernel (320 threads): scatter (blocks < PBLK) runs CONCURRENTLY with
// the MFMA feat GEMM (blocks > PBLK). Block PBLK computes ee.
// (byte-identical to round 12 — known-good)
// ---------------------------------------------------------------------------
#define XS_STRIDE 136   // 128 + 8 pad shorts
__global__ __launch_bounds__(320) void feat_scatter_kernel(
    const float* __restrict__ x,
    const short* __restrict__ WTb,
    const float* __restrict__ edge_emb,
    const float* __restrict__ W_e,
    const float* __restrict__ attn_e,
    const int* __restrict__ src, const int* __restrict__ dst,
    const int* __restrict__ etype,
    __hip_bfloat16* __restrict__ featb,
    float* __restrict__ el,
    float* __restrict__ er,
    float* __restrict__ ee,
    int* __restrict__ cnt, int2* __restrict__ sc_bucket)
{
    __shared__ __align__(16) char smem[FROWS * XS_STRIDE * 2];   // 8.7 KB union
    const int t = threadIdx.x;
    const int b = blockIdx.x;

    if (b < PBLK) {
        int* h = (int*)smem;                 // NBUCK ints
        int buld[13];                        // ceil(EPB/320) = 13
        for (int j = t; j < NBUCK; j += 320) h[j] = 0;
        __syncthreads();
        const int e0 = b * EPB;
        int k = 0;
        for (int i = t; i < EPB; i += 320, ++k) {
            const int dn = dst[e0 + i];
            const int bu = dn / NPB;
            const int ld = dn - bu * NPB;
            buld[k] = bu | (ld << 16);
            atomicAdd(&h[bu], 1);
        }
        __syncthreads();
        for (int j = t; j < NBUCK; j += 320) {
            const int c = h[j];
            h[j] = j * BCAP + (c ? atomicAdd(&cnt[j], c) : 0);  // region cursor
        }
        __syncthreads();
        k = 0;
        for (int i = t; i < EPB; i += 320, ++k) {
            const int e  = e0 + i;
            const int bu = buld[k] & 0xFFFF;
            const int ld = buld[k] >> 16;
            const int slot = atomicAdd(&h[bu], 1);
            sc_bucket[slot] = make_int2(src[e], e | (etype[e] << 21) | (ld << 23));
        }
        return;
    }

    if (b == PBLK) {
        const int wv = t >> 6, e = t & 63;
        for (int j = wv; j < N_ETYPES * HEADS; j += 5) {
            const int ty = j >> 2, h = j & 3;
            float ef = 0.f;
#pragma unroll
            for (int k = 0; k < EDGE_FEATS; ++k)
                ef += edge_emb[ty * EDGE_FEATS + k] *
                      W_e[k * (HEADS * EDGE_FEATS) + h * EDGE_FEATS + e];
            float v = ef * attn_e[h * EDGE_FEATS + e];
#pragma unroll
            for (int m = 1; m < 64; m <<= 1) v += __shfl_xor(v, m, 64);
            if (e == 0) ee[ty * HEADS + h] = v;
        }
        return;
    }

    short* Xs = (short*)smem;
    const int row0 = (b - PBLK - 1) * FROWS;
    if (t < 256) {
        const int r = t >> 3, k0 = (t & 7) * 16;
        const float4* xg = (const float4*)(x + (size_t)(row0 + r) * IN_FEATS + k0);
        const float4 v0 = xg[0], v1 = xg[1], v2 = xg[2], v3 = xg[3];
        s16x8 p0, p1;
        p0[0] = f2bs(v0.x); p0[1] = f2bs(v0.y); p0[2] = f2bs(v0.z); p0[3] = f2bs(v0.w);
        p0[4] = f2bs(v1.x); p0[5] = f2bs(v1.y); p0[6] = f2bs(v1.z); p0[7] = f2bs(v1.w);
        p1[0] = f2bs(v2.x); p1[1] = f2bs(v2.y); p1[2] = f2bs(v2.z); p1[3] = f2bs(v2.w);
        p1[4] = f2bs(v3.x); p1[5] = f2bs(v3.y); p1[6] = f2bs(v3.z); p1[7] = f2bs(v3.w);
        *(s16x8*)&Xs[r * XS_STRIDE + k0]     = p0;
        *(s16x8*)&Xs[r * XS_STRIDE + k0 + 8] = p1;
    }

    const int w    = t >> 6;                 // 0..4 (wave 4 = el/er tile)
    const int lane = t & 63;
    const int m    = lane & 15;
    const int q    = lane >> 4;

    s16x8 bfr[4];
#pragma unroll
    for (int kb = 0; kb < 4; ++kb)
        bfr[kb] = *(const s16x8*)(WTb + (size_t)(w * 16 + m) * IN_FEATS + kb * 32 + q * 8);

    __syncthreads();

#pragma unroll
    for (int rg = 0; rg < 2; ++rg) {
        f32x4 acc = {0.f, 0.f, 0.f, 0.f};
#pragma unroll
        for (int kb = 0; kb < 4; ++kb) {
            const s16x8 af = *(const s16x8*)&Xs[(rg * 16 + m) * XS_STRIDE + kb * 32 + q * 8];
            acc = __builtin_amdgcn_mfma_f32_16x16x32_bf16(af, bfr[kb], acc, 0, 0, 0);
        }
        if (w < 4) {
#pragma unroll
            for (int r = 0; r < 4; ++r) {
                const int row = row0 + rg * 16 + q * 4 + r;
                featb[(size_t)row * HD + w * 16 + m] = __float2bfloat16(acc[r]);
            }
        } else {
#pragma unroll
            for (int r = 0; r < 4; ++r) {
                const int row = row0 + rg * 16 + q * 4 + r;
                if (m < 4)      el[row * HEADS + m]       = acc[r];
                else if (m < 8) er[row * HEADS + (m - 4)] = acc[r];
            }
        }
    }
}

// ---------------------------------------------------------------------------
// FUSED CSR + aggregation: one block per (bucket, node-half). Pass A:
// histogram bucket from global; scan. Pass B: re-read (L2-hot) and rebin
// into LDS ssort. Then per-wave node processing (verified r9/r12 agg code,
// sc reads switched to LDS ssort; sl/elds staging eliminated).
// Eliminates bucket_csr_kernel + its 12.8MB writeback + ptr/deg + agg's
// sorted-sc global re-read. 3 total dispatches.
// ---------------------------------------------------------------------------
__global__ __launch_bounds__(256) void bucket_agg_kernel(
    const int2* __restrict__ sc_bucket, const int* __restrict__ cnt,
    const float* __restrict__ el, const float* __restrict__ er,
    const float* __restrict__ ee, const __hip_bfloat16* __restrict__ featb,
    float* __restrict__ rst, float* __restrict__ a_out)
{
    __shared__ int2  ssort[BCAP];              // 20.5 KB sorted bucket edges
    __shared__ int   sdeg4[4][128];            // 2 KB per-wave hists
    __shared__ int   sdg[128];                 // deg per local node
    __shared__ int   soff[128];                // exclusive offsets
    __shared__ int   scur[128];                // rebin cursors
    __shared__ float w_lds[4][MAXD_LDS * HEADS];   // 8 KB
    const int t    = threadIdx.x;
    const int bb   = blockIdx.x;
    const int b    = bb >> 1;                  // bucket
    const int half = bb & 1;                   // node-range half
    const int wid  = t >> 6;
    const int lane = t & 63;

    sdeg4[0][t & 127] = 0; sdeg4[1][t & 127] = 0;
    if (t < 128) { sdeg4[2][t] = 0; sdeg4[3][t] = 0; }
    __syncthreads();
    const int count = min(cnt[b], BCAP);
    const int base  = b * BCAP;

    // pass A: histogram (HBM for first block of pair, L2-hot for second)
    for (int i = t; i < count; i += 256)
        atomicAdd(&sdeg4[wid][(sc_bucket[base + i].y >> 23) & 0x7F], 1);
    __syncthreads();
    int orig = 0;
    if (t < 128) {
        orig = sdeg4[0][t] + sdeg4[1][t] + sdeg4[2][t] + sdeg4[3][t];
        sdg[t] = orig;
    }
    __syncthreads();
    for (int off = 1; off < 128; off <<= 1) {
        const int v = (t < 128 && t >= off) ? sdg[t - off] : 0;
        __syncthreads();
        if (t < 128) sdg[t] += v;
        __syncthreads();
    }
    if (t < 128) {
        const int excl = sdg[t] - orig;
        soff[t] = excl;
        scur[t] = excl;
        sdg[t]  = orig;                        // sdg now holds deg
    }
    __syncthreads();
    // pass B: rebin into LDS (re-read is L2-hot — bucket just fetched)
    for (int i = t; i < count; i += 256) {
        const int2 v = sc_bucket[base + i];
        const int ld = (v.y >> 23) & 0x7F;
        const int slot = atomicAdd(&scur[ld], 1);
        ssort[slot] = make_int2(v.x, v.y & 0x7FFFFF);   // {src, e|ty<<21}
    }
    __syncthreads();

    // node loop: half 0 -> [0,63), half 1 -> [63,125); one node per wave-iter
    const int ln0 = half ? 63 : 0;
    const int ln1 = half ? NPB : 63;
    const ushort* fb = (const ushort*)featb;

    for (int ln = ln0 + wid; ln < ln1; ln += 4) {
        const int n   = b * NPB + ln;
        const int p0  = soff[ln];
        const int deg = sdg[ln];
        float* wl = w_lds[wid];

        if (deg <= MAXD_LDS) {
            // ---- phase 1: weights, one lane per (edge, head) ----
            const int eo = lane >> 2;          // edge in group of 16
            const int hA = lane & 3;           // head
            const float er_n = er[n * HEADS + hA];
            const float g0 = ee[hA], g1 = ee[HEADS + hA], g2 = ee[2 * HEADS + hA];

            float zacc = 0.f;
            for (int i0 = 0; i0 < deg; i0 += 32) {
                const int idxA = i0 + eo;
                const int idxB = i0 + 16 + eo;
                const bool pA = idxA < deg;
                const bool pB = idxB < deg;
                int2 vA = make_int2(0, 0), vB = make_int2(0, 0);
                if (pA) vA = ssort[p0 + idxA];            // LDS
                if (pB) vB = ssort[p0 + idxB];
                float eA = 0.f, eB = 0.f;
                if (pA) eA = el[vA.x * HEADS + hA];       // both gathers issued
                if (pB) eB = el[vB.x * HEADS + hA];
                if (pA) {
                    const int ty = vA.y >> 21;
                    float s = eA + er_n + ((ty == 0) ? g0 : ((ty == 1) ? g1 : g2));
                    s = s > 0.f ? s : NEG_SLOPE * s;
                    const float w = __expf(s);
                    wl[idxA * HEADS + hA] = w;
                    zacc += w;
                }
                if (pB) {
                    const int ty = vB.y >> 21;
                    float s = eB + er_n + ((ty == 0) ? g0 : ((ty == 1) ? g1 : g2));
                    s = s > 0.f ? s : NEG_SLOPE * s;
                    const float w = __expf(s);
                    wl[idxB * HEADS + hA] = w;
                    zacc += w;
                }
            }
            // butterfly over eo bits {4,8,16,32}; every lane holds z[lane&3]
            zacc += __shfl_xor(zacc, 4, 64);
            zacc += __shfl_xor(zacc, 8, 64);
            zacc += __shfl_xor(zacc, 16, 64);
            zacc += __shfl_xor(zacc, 32, 64);
            const float izA = (deg > 0) ? __frcp_rn(zacc) : 0.f;

            // ---- a_out epilogue: 4 lanes (heads) per edge, 16B granule ----
            for (int idx = eo; idx < deg; idx += 16)
                a_out[((size_t)(ssort[p0 + idx].y & 0x1FFFFF) << 2) + hA] =
                    wl[idx * HEADS + hA] * izA;

            // ---- phase 2: 8 edges x 8 lanes, 16B loads, 16 edges in flight ----
            const int q8 = lane >> 3;
            const int c8 = lane & 7;
            const int h8 = c8 >> 1;
            // z[h8] lives at lane h8
            const float inv_z = (deg > 0) ? __frcp_rn(__shfl(zacc, h8, 64)) : 0.f;

            float a0 = 0.f, a1 = 0.f, a2 = 0.f, a3 = 0.f;
            float a4 = 0.f, a5 = 0.f, a6 = 0.f, a7 = 0.f;
            int i = 0;
            for (; i + 16 <= deg; i += 16) {
                const int idxA = i + q8, idxB = i + 8 + q8;
                const int sA = ssort[p0 + idxA].x;
                const int sB = ssort[p0 + idxB].x;
                const float wA = wl[idxA * HEADS + h8];
                const float wB = wl[idxB * HEADS + h8];
                const uint4 fA = *(const uint4*)(fb + ((size_t)sA << 6) + (c8 << 3));
                const uint4 fB = *(const uint4*)(fb + ((size_t)sB << 6) + (c8 << 3));
                a0 += __uint_as_float(fA.x << 16) * wA;
                a1 += __uint_as_float(fA.x & 0xFFFF0000u) * wA;
                a2 += __uint_as_float(fA.y << 16) * wA;
                a3 += __uint_as_float(fA.y & 0xFFFF0000u) * wA;
                a4 += __uint_as_float(fA.z << 16) * wA;
                a5 += __uint_as_float(fA.z & 0xFFFF0000u) * wA;
                a6 += __uint_as_float(fA.w << 16) * wA;
                a7 += __uint_as_float(fA.w & 0xFFFF0000u) * wA;
                a0 += __uint_as_float(fB.x << 16) * wB;
                a1 += __uint_as_float(fB.x & 0xFFFF0000u) * wB;
                a2 += __uint_as_float(fB.y << 16) * wB;
                a3 += __uint_as_float(fB.y & 0xFFFF0000u) * wB;
                a4 += __uint_as_float(fB.z << 16) * wB;
                a5 += __uint_as_float(fB.z & 0xFFFF0000u) * wB;
                a6 += __uint_as_float(fB.w << 16) * wB;
                a7 += __uint_as_float(fB.w & 0xFFFF0000u) * wB;
            }
            if (i + 8 <= deg) {
                const int idx = i + q8;
                const int sA = ssort[p0 + idx].x;
                const float wA = wl[idx * HEADS + h8];
                const uint4 fA = *(const uint4*)(fb + ((size_t)sA << 6) + (c8 << 3));
                a0 += __uint_as_float(fA.x << 16) * wA;
                a1 += __uint_as_float(fA.x & 0xFFFF0000u) * wA;
                a2 += __uint_as_float(fA.y << 16) * wA;
                a3 += __uint_as_float(fA.y & 0xFFFF0000u) * wA;
                a4 += __uint_as_float(fA.z << 16) * wA;
                a5 += __uint_as_float(fA.z & 0xFFFF0000u) * wA;
                a6 += __uint_as_float(fA.w << 16) * wA;
                a7 += __uint_as_float(fA.w & 0xFFFF0000u) * wA;
                i += 8;
            }
            if (i + q8 < deg) {
                const int idx = i + q8;
                const int sA = ssort[p0 + idx].x;
                const float wA = wl[idx * HEADS + h8];
                const uint4 fA = *(const uint4*)(fb + ((size_t)sA << 6) + (c8 << 3));
                a0 += __uint_as_float(fA.x << 16) * wA;
                a1 += __uint_as_float(fA.x & 0xFFFF0000u) * wA;
                a2 += __uint_as_float(fA.y << 16) * wA;
                a3 += __uint_as_float(fA.y & 0xFFFF0000u) * wA;
                a4 += __uint_as_float(fA.z << 16) * wA;
                a5 += __uint_as_float(fA.z & 0xFFFF0000u) * wA;
                a6 += __uint_as_float(fA.w << 16) * wA;
                a7 += __uint_as_float(fA.w & 0xFFFF0000u) * wA;
            }
            // reduce over 8 edge slots (lane bits 3..5)
            a0 += __shfl_xor(a0, 8, 64); a0 += __shfl_xor(a0, 16, 64); a0 += __shfl_xor(a0, 32, 64);
            a1 += __shfl_xor(a1, 8, 64); a1 += __shfl_xor(a1, 16, 64); a1 += __shfl_xor(a1, 32, 64);
            a2 += __shfl_xor(a2, 8, 64); a2 += __shfl_xor(a2, 16, 64); a2 += __shfl_xor(a2, 32, 64);
            a3 += __shfl_xor(a3, 8, 64); a3 += __shfl_xor(a3, 16, 64); a3 += __shfl_xor(a3, 32, 64);
            a4 += __shfl_xor(a4, 8, 64); a4 += __shfl_xor(a4, 16, 64); a4 += __shfl_xor(a4, 32, 64);
            a5 += __shfl_xor(a5, 8, 64); a5 += __shfl_xor(a5, 16, 64); a5 += __shfl_xor(a5, 32, 64);
            a6 += __shfl_xor(a6, 8, 64); a6 += __shfl_xor(a6, 16, 64); a6 += __shfl_xor(a6, 32, 64);
            a7 += __shfl_xor(a7, 8, 64); a7 += __shfl_xor(a7, 16, 64); a7 += __shfl_xor(a7, 32, 64);
            if (q8 == 0) {
                f32x4 v0 = {a0 * inv_z, a1 * inv_z, a2 * inv_z, a3 * inv_z};
                f32x4 v1 = {a4 * inv_z, a5 * inv_z, a6 * inv_z, a7 * inv_z};
                *(f32x4*)(rst + (size_t)n * HD + (c8 << 3))     = v0;
                *(f32x4*)(rst + (size_t)n * HD + (c8 << 3) + 4) = v1;
            }
        } else {
            // ---- rare big-degree path (edges still fully in ssort) ----
            const int hA = lane & 3;
            const int eo = lane >> 2;
            const float er_nA = er[n * HEADS + hA];
            const float b0 = ee[hA], b1 = ee[HEADS + hA], b2 = ee[2 * HEADS + hA];
            float zacc = 0.f;
            for (int bs = 0; bs < deg; bs += 16) {
                const int idx = bs + eo;
                if (idx < deg) {
                    const int2 v = ssort[p0 + idx];
                    const int ty = v.y >> 21;
                    float s = el[v.x * HEADS + hA] + er_nA +
                              ((ty == 0) ? b0 : ((ty == 1) ? b1 : b2));
                    s = s > 0.f ? s : NEG_SLOPE * s;
                    zacc += __expf(s);
                }
            }
#pragma unroll
            for (int m = 4; m < 64; m <<= 1) zacc += __shfl_xor(zacc, m, 64);
            const int h = lane >> 4;
            const int d = lane & 15;
            // every lane holds z[lane&3]; z[h] lives at lane h
            const float inv_z = __frcp_rn(__shfl(zacc, h, 64));
            const float er_n = er[n * HEADS + h];
            const float g0 = ee[h], g1 = ee[HEADS + h], g2 = ee[2 * HEADS + h];
            float racc = 0.f;
            for (int i = 0; i < deg; ++i) {
                const int2 v = ssort[p0 + i];
                const int ty = v.y >> 21;
                float s = el[v.x * HEADS + h] + er_n +
                          ((ty == 0) ? g0 : ((ty == 1) ? g1 : g2));
                s = s > 0.f ? s : NEG_SLOPE * s;
                const float a = __expf(s) * inv_z;
                racc += __bfloat162float(featb[(size_t)v.x * HD + lane]) * a;
                if (d == 0) a_out[((size_t)(v.y & 0x1FFFFF) << 2) + h] = a;
            }
            rst[(size_t)n * HD + lane] = racc;
        }
    }
}

extern "C" void kernel_launch(void* const* d_in, const int* in_sizes, int n_in,
                              void* d_out, int out_size, void* d_ws, size_t ws_size,
                              hipStream_t stream)
{
    const float* x        = (const float*)d_in[0];
    const float* W        = (const float*)d_in[1];
    const float* W_e      = (const float*)d_in[2];
    const float* attn_l   = (const float*)d_in[3];
    const float* attn_r   = (const float*)d_in[4];
    const float* attn_e   = (const float*)d_in[5];
    const float* edge_emb = (const float*)d_in[6];
    const int* src   = (const int*)d_in[7];
    const int* dst   = (const int*)d_in[8];
    const int* etype = (const int*)d_in[9];

    float* out     = (float*)d_out;
    float* rst_out = out;                              // N*H*D
    float* a_out   = out + (size_t)N_NODES * HD;       // E*H

    char* w = (char*)d_ws;
    __hip_bfloat16* featb = (__hip_bfloat16*)w; w += (size_t)N_NODES * HD * 2;   // 12.8 MB
    float* el    = (float*)w;  w += (size_t)N_NODES * HEADS * 4;    //  1.6 MB
    float* er    = (float*)w;  w += (size_t)N_NODES * HEADS * 4;    //  1.6 MB
    float* ee    = (float*)w;  w += 64;
    int*   cnt   = (int*)w;    w += (size_t)(NBUCK + 8) * 4;        //  3.2 KB
    short* WTb   = (short*)w;  w += (size_t)WTROWS * IN_FEATS * 2;  //   20 KB
    int2*  sc_bucket = (int2*)w; w += ((size_t)NBUCK * BCAP + 2048) * 8;  // 16.4 MB
    // total ~32.5 MB

    // 1) WTb[80][128] (feat + el/er columns) + zero(cnt)
    wt_prep_kernel<<<(WTROWS * IN_FEATS) / 256, 256, 0, stream>>>(
        W, attn_l, attn_r, WTb, cnt);

    // 2) FUSED: scatter (0..399) || ee (400) || feat GEMM w/ el-er tile (401..)
    feat_scatter_kernel<<<PBLK + 1 + NFEAT, 320, 0, stream>>>(
        x, WTb, edge_emb, W_e, attn_e,
        src, dst, etype, featb, el, er, ee, cnt, sc_bucket);

    // 3) FUSED CSR + aggregation + a_out (2 blocks per bucket, node halves)
    bucket_agg_kernel<<<2 * NBUCK, 256, 0, stream>>>(
        sc_bucket, cnt, el, er, ee, featb, rst_out, a_out);
}

// Round 14
// 246.815 us; speedup vs baseline: 1.1514x; 1.1514x over previous
//
#include <hip/hip_runtime.h>
#include <hip/hip_bf16.h>

#define N_NODES   100000
#define N_EDGES   1600000
#define N_ETYPES  3
#define IN_FEATS  128
#define HEADS     4
#define OUT_FEATS 16
#define EDGE_FEATS 64
#define HD        64            // HEADS*OUT_FEATS
#define NEG_SLOPE 0.2f
#define MAXD_LDS  128           // agg fast-path max degree (Poisson(16): P(>128)~0)

#define NBUCK     800           // buckets for counting sort
#define NPB       125           // nodes per bucket (800*125 = N_NODES)
#define PBLK      400           // scatter blocks
#define EPB       4000          // edges per scatter block
#define BCAP      2560          // fixed bucket-region capacity (mean 2000, 12.5 sigma)
#define FROWS     32            // rows per feat block (100000/32 = 3125 exact)
#define NFEAT     (N_NODES / FROWS)   // 3125
#define WTROWS    80            // 64 feat cols + 4 el + 4 er + 8 zero-pad

// fused grid: [0,PBLK) scatter | PBLK service(ee) | (PBLK, PBLK+NFEAT] feat
// sc_bucket payload (int2): {src, e | ty<<21 | ld<<23}; after csr: {src, e | ty<<21}

typedef short s16x8 __attribute__((ext_vector_type(8)));
typedef float f32x4 __attribute__((ext_vector_type(4)));

__device__ __forceinline__ short f2bs(float f) {
    __hip_bfloat16 h = __float2bfloat16(f);
    return *reinterpret_cast<short*>(&h);
}

// ---------------------------------------------------------------------------
// Prep: WTb bf16 [80][128]. Rows 0..63: W^T. Rows 64..67: Wl (el cols),
// 68..71: Wr (er cols), 72..79: zero. el/er thus become extra GEMM columns —
// the feat kernel's shuffle epilogue is eliminated. Block 0 zeroes cnt.
// ---------------------------------------------------------------------------
__global__ __launch_bounds__(256) void wt_prep_kernel(
    const float* __restrict__ W,
    const float* __restrict__ attn_l,
    const float* __restrict__ attn_r,
    short* __restrict__ WTb, int* __restrict__ cnt)
{
    const int t = blockIdx.x * 256 + threadIdx.x;   // 0..10239
    const int n = t >> 7, k = t & 127;
    short v;
    if (n < 64) {
        v = f2bs(W[k * HD + n]);
    } else if (n < 72) {
        const int h = (n - 64) & 3;
        const float* av = (n < 68) ? attn_l : attn_r;
        float s = 0.f;
#pragma unroll
        for (int d = 0; d < OUT_FEATS; ++d)
            s += W[k * HD + h * OUT_FEATS + d] * av[h * OUT_FEATS + d];
        v = f2bs(s);
    } else {
        v = 0;
    }
    WTb[n * IN_FEATS + k] = v;
    if (blockIdx.x == 0)
        for (int j = threadIdx.x; j < NBUCK; j += 256) cnt[j] = 0;
}

// ---------------------------------------------------------------------------
// FUSED kernel (320 threads): scatter (blocks < PBLK) runs CONCURRENTLY with
// the MFMA feat GEMM (blocks > PBLK). Block PBLK computes ee.
// Feat path: 5 waves — waves 0..3 produce feat cols, wave 4 produces the
// el/er tile directly from MFMA acc (no cross-lane reduction needed).
// ---------------------------------------------------------------------------
#define XS_STRIDE 136   // 128 + 8 pad shorts
__global__ __launch_bounds__(320) void feat_scatter_kernel(
    const float* __restrict__ x,
    const short* __restrict__ WTb,
    const float* __restrict__ edge_emb,
    const float* __restrict__ W_e,
    const float* __restrict__ attn_e,
    const int* __restrict__ src, const int* __restrict__ dst,
    const int* __restrict__ etype,
    __hip_bfloat16* __restrict__ featb,
    float* __restrict__ el,
    float* __restrict__ er,
    float* __restrict__ ee,
    int* __restrict__ cnt, int2* __restrict__ sc_bucket)
{
    __shared__ __align__(16) char smem[FROWS * XS_STRIDE * 2];   // 8.7 KB union
    const int t = threadIdx.x;
    const int b = blockIdx.x;

    if (b < PBLK) {
        // ---- scatter path: LDS hist -> region claim -> LDS-cursor scatter ----
        int* h = (int*)smem;                 // NBUCK ints (3.2 KB of union)
        int buld[13];                        // ceil(EPB/320) = 13
        for (int j = t; j < NBUCK; j += 320) h[j] = 0;
        __syncthreads();
        const int e0 = b * EPB;
        int k = 0;
        for (int i = t; i < EPB; i += 320, ++k) {
            const int dn = dst[e0 + i];
            const int bu = dn / NPB;
            const int ld = dn - bu * NPB;
            buld[k] = bu | (ld << 16);
            atomicAdd(&h[bu], 1);
        }
        __syncthreads();
        for (int j = t; j < NBUCK; j += 320) {
            const int c = h[j];
            h[j] = j * BCAP + (c ? atomicAdd(&cnt[j], c) : 0);  // region cursor
        }
        __syncthreads();
        k = 0;
        for (int i = t; i < EPB; i += 320, ++k) {
            const int e  = e0 + i;
            const int bu = buld[k] & 0xFFFF;
            const int ld = buld[k] >> 16;
            const int slot = atomicAdd(&h[bu], 1);
            sc_bucket[slot] = make_int2(src[e], e | (etype[e] << 21) | (ld << 23));
        }
        return;
    }

    if (b == PBLK) {
        // ---- service block: ee (12 jobs over 5 waves) ----
        const int wv = t >> 6, e = t & 63;
        for (int j = wv; j < N_ETYPES * HEADS; j += 5) {
            const int ty = j >> 2, h = j & 3;
            float ef = 0.f;
#pragma unroll
            for (int k = 0; k < EDGE_FEATS; ++k)
                ef += edge_emb[ty * EDGE_FEATS + k] *
                      W_e[k * (HEADS * EDGE_FEATS) + h * EDGE_FEATS + e];
            float v = ef * attn_e[h * EDGE_FEATS + e];
#pragma unroll
            for (int m = 1; m < 64; m <<= 1) v += __shfl_xor(v, m, 64);
            if (e == 0) ee[ty * HEADS + h] = v;
        }
        return;
    }

    // ---- feat path: 32 rows/block MFMA GEMM; wave 4 = el/er tile ----
    short* Xs = (short*)smem;                // FROWS*XS_STRIDE shorts
    const int row0 = (b - PBLK - 1) * FROWS;
    if (t < 256) {   // stage x -> bf16 LDS: 16 elems/thread
        const int r = t >> 3, k0 = (t & 7) * 16;
        const float4* xg = (const float4*)(x + (size_t)(row0 + r) * IN_FEATS + k0);
        const float4 v0 = xg[0], v1 = xg[1], v2 = xg[2], v3 = xg[3];
        s16x8 p0, p1;
        p0[0] = f2bs(v0.x); p0[1] = f2bs(v0.y); p0[2] = f2bs(v0.z); p0[3] = f2bs(v0.w);
        p0[4] = f2bs(v1.x); p0[5] = f2bs(v1.y); p0[6] = f2bs(v1.z); p0[7] = f2bs(v1.w);
        p1[0] = f2bs(v2.x); p1[1] = f2bs(v2.y); p1[2] = f2bs(v2.z); p1[3] = f2bs(v2.w);
        p1[4] = f2bs(v3.x); p1[5] = f2bs(v3.y); p1[6] = f2bs(v3.z); p1[7] = f2bs(v3.w);
        *(s16x8*)&Xs[r * XS_STRIDE + k0]     = p0;
        *(s16x8*)&Xs[r * XS_STRIDE + k0 + 8] = p1;
    }

    const int w    = t >> 6;                 // 0..4 (wave 4 = el/er tile)
    const int lane = t & 63;
    const int m    = lane & 15;
    const int q    = lane >> 4;

    // B-fragments direct from WTb (L1-resident 20KB); wave 4 hits rows 64..79
    s16x8 bfr[4];
#pragma unroll
    for (int kb = 0; kb < 4; ++kb)
        bfr[kb] = *(const s16x8*)(WTb + (size_t)(w * 16 + m) * IN_FEATS + kb * 32 + q * 8);

    __syncthreads();

#pragma unroll
    for (int rg = 0; rg < 2; ++rg) {
        f32x4 acc = {0.f, 0.f, 0.f, 0.f};
#pragma unroll
        for (int kb = 0; kb < 4; ++kb) {
            const s16x8 af = *(const s16x8*)&Xs[(rg * 16 + m) * XS_STRIDE + kb * 32 + q * 8];
            acc = __builtin_amdgcn_mfma_f32_16x16x32_bf16(af, bfr[kb], acc, 0, 0, 0);
        }
        if (w < 4) {
#pragma unroll
            for (int r = 0; r < 4; ++r) {
                const int row = row0 + rg * 16 + q * 4 + r;
                featb[(size_t)row * HD + w * 16 + m] = __float2bfloat16(acc[r]);
            }
        } else {
#pragma unroll
            for (int r = 0; r < 4; ++r) {
                const int row = row0 + rg * 16 + q * 4 + r;
                if (m < 4)      el[row * HEADS + m]       = acc[r];
                else if (m < 8) er[row * HEADS + (m - 4)] = acc[r];
            }
        }
    }
}

// ---------------------------------------------------------------------------
// CSR finalize IN-PLACE: one block per bucket; full LDS stage, bin over 125
// local nodes, write back into the SAME fixed region. Emits ptr[n] + deg[n].
// ---------------------------------------------------------------------------
__global__ __launch_bounds__(256) void bucket_csr_kernel(
    int2* __restrict__ sc_bucket, const int* __restrict__ cnt,
    int* __restrict__ ptr, int* __restrict__ deg)
{
    __shared__ int2 sbuf[BCAP];       // 20.5 KB
    __shared__ int sdeg4[4][128];     // per-wave hists, 2 KB
    __shared__ int sdg[128];
    __shared__ int scur[128];
    const int t = threadIdx.x, b = blockIdx.x;
    const int wid = t >> 6;

    sdeg4[0][t & 127] = 0; sdeg4[1][t & 127] = 0;
    if (t < 128) { sdeg4[2][t] = 0; sdeg4[3][t] = 0; }
    __syncthreads();
    const int count = min(cnt[b], BCAP);
    const int base  = b * BCAP;

    for (int i = t; i < count; i += 256) {
        const int2 v = sc_bucket[base + i];
        sbuf[i] = v;
        atomicAdd(&sdeg4[wid][(v.y >> 23) & 0x7F], 1);
    }
    __syncthreads();
    int orig = 0;
    if (t < 128) {
        orig = sdeg4[0][t] + sdeg4[1][t] + sdeg4[2][t] + sdeg4[3][t];
        sdg[t] = orig;
    }
    __syncthreads();
    for (int off = 1; off < 128; off <<= 1) {
        const int v = (t < 128 && t >= off) ? sdg[t - off] : 0;
        __syncthreads();
        if (t < 128) sdg[t] += v;
        __syncthreads();
    }
    if (t < 128) {
        const int excl = sdg[t] - orig;
        if (t < NPB) {
            ptr[b * NPB + t] = base + excl;
            deg[b * NPB + t] = orig;
        }
        scur[t] = base + excl;           // region-local slot base
    }
    __syncthreads();
    for (int i = t; i < count; i += 256) {
        const int2 v = sbuf[i];
        const int ld = (v.y >> 23) & 0x7F;
        const int slot = atomicAdd(&scur[ld], 1);
        sc_bucket[slot] = make_int2(v.x, v.y & 0x7FFFFF);   // {src, e|ty<<21}
    }
}

// ---------------------------------------------------------------------------
// Kernel C: per-dst aggregation + FUSED a_out, one wave per node.
// Phase 1 (x2 pipelined): exp ONCE per (e,h); w,src,ey -> LDS; z reduce.
// After the {4,8,16,32} butterfly every lane holds z[lane&3]; z[h] broadcast
// from LANE h. Epilogue: a_out[ey*4+h] = w*inv_z (16B granule per edge).
// Phase 2 (x2 pipelined): 8 edges x 8 lanes, 16B dwordx4 feat loads.
// ---------------------------------------------------------------------------
__global__ __launch_bounds__(256) void agg_kernel(
    const int2* __restrict__ sc_csr, const int* __restrict__ ptr,
    const int* __restrict__ deg_arr,
    const float* __restrict__ el, const float* __restrict__ er,
    const float* __restrict__ ee, const __hip_bfloat16* __restrict__ featb,
    float* __restrict__ rst, float* __restrict__ a_out)
{
    __shared__ float w_lds[4][MAXD_LDS * HEADS];   // 8 KB
    __shared__ int   s_lds[4][MAXD_LDS];           // 2 KB
    __shared__ int   e_lds[4][MAXD_LDS];           // 2 KB
    const int wid  = threadIdx.x >> 6;
    const int lane = threadIdx.x & 63;
    const int n    = blockIdx.x * 4 + wid;

    const int p0  = ptr[n];
    const int deg = deg_arr[n];
    float* wl = w_lds[wid];
    int*   sl = s_lds[wid];
    int*   elds = e_lds[wid];
    const ushort* fb = (const ushort*)featb;

    if (deg <= MAXD_LDS) {
        // ---- phase 1: weights, one lane per (edge, head), 32 edges/iter ----
        const int eo = lane >> 2;          // edge in group of 16
        const int hA = lane & 3;           // head
        const float er_n = er[n * HEADS + hA];
        const float g0 = ee[hA], g1 = ee[HEADS + hA], g2 = ee[2 * HEADS + hA];

        float zacc = 0.f;
        for (int i0 = 0; i0 < deg; i0 += 32) {
            const int idxA = i0 + eo;
            const int idxB = i0 + 16 + eo;
            const bool pA = idxA < deg;
            const bool pB = idxB < deg;
            int2 vA = make_int2(0, 0), vB = make_int2(0, 0);
            if (pA) vA = sc_csr[p0 + idxA];          // both loads issued
            if (pB) vB = sc_csr[p0 + idxB];
            float eA = 0.f, eB = 0.f;
            if (pA) eA = el[vA.x * HEADS + hA];      // both gathers issued
            if (pB) eB = el[vB.x * HEADS + hA];
            if (pA) {
                const int ty = vA.y >> 21;
                float s = eA + er_n + ((ty == 0) ? g0 : ((ty == 1) ? g1 : g2));
                s = s > 0.f ? s : NEG_SLOPE * s;
                const float w = __expf(s);
                wl[idxA * HEADS + hA] = w;
                if (hA == 0) sl[idxA] = vA.x;
                if (hA == 1) elds[idxA] = vA.y & 0x1FFFFF;
                zacc += w;
            }
            if (pB) {
                const int ty = vB.y >> 21;
                float s = eB + er_n + ((ty == 0) ? g0 : ((ty == 1) ? g1 : g2));
                s = s > 0.f ? s : NEG_SLOPE * s;
                const float w = __expf(s);
                wl[idxB * HEADS + hA] = w;
                if (hA == 0) sl[idxB] = vB.x;
                if (hA == 1) elds[idxB] = vB.y & 0x1FFFFF;
                zacc += w;
            }
        }
        // reduce z over edge groups (lane bits 2..5); every lane holds z[lane&3]
        zacc += __shfl_xor(zacc, 4, 64);
        zacc += __shfl_xor(zacc, 8, 64);
        zacc += __shfl_xor(zacc, 16, 64);
        zacc += __shfl_xor(zacc, 32, 64);
        const float izA = (deg > 0) ? __frcp_rn(zacc) : 0.f;

        // ---- a_out epilogue: 4 lanes (heads) write one 16B granule/edge ----
        for (int idx = eo; idx < deg; idx += 16)
            a_out[((size_t)elds[idx] << 2) + hA] = wl[idx * HEADS + hA] * izA;

        // ---- phase 2: accumulate, 16 edges in flight (2 x 8-edge groups) ----
        const int q8 = lane >> 3;          // edge slot 0..7
        const int c8 = lane & 7;           // col group: cols 8*c8 .. 8*c8+7
        const int h8 = c8 >> 1;            // head of those cols
        // z[h8] lives at lane h8
        const float inv_z = (deg > 0) ? __frcp_rn(__shfl(zacc, h8, 64)) : 0.f;

        float a0 = 0.f, a1 = 0.f, a2 = 0.f, a3 = 0.f;
        float a4 = 0.f, a5 = 0.f, a6 = 0.f, a7 = 0.f;
        int i = 0;
        for (; i + 16 <= deg; i += 16) {
            const int idxA = i + q8, idxB = i + 8 + q8;
            const int sA = sl[idxA], sB = sl[idxB];
            const float wA = wl[idxA * HEADS + h8];
            const float wB = wl[idxB * HEADS + h8];
            const uint4 fA = *(const uint4*)(fb + ((size_t)sA << 6) + (c8 << 3));
            const uint4 fB = *(const uint4*)(fb + ((size_t)sB << 6) + (c8 << 3));
            a0 += __uint_as_float(fA.x << 16) * wA;
            a1 += __uint_as_float(fA.x & 0xFFFF0000u) * wA;
            a2 += __uint_as_float(fA.y << 16) * wA;
            a3 += __uint_as_float(fA.y & 0xFFFF0000u) * wA;
            a4 += __uint_as_float(fA.z << 16) * wA;
            a5 += __uint_as_float(fA.z & 0xFFFF0000u) * wA;
            a6 += __uint_as_float(fA.w << 16) * wA;
            a7 += __uint_as_float(fA.w & 0xFFFF0000u) * wA;
            a0 += __uint_as_float(fB.x << 16) * wB;
            a1 += __uint_as_float(fB.x & 0xFFFF0000u) * wB;
            a2 += __uint_as_float(fB.y << 16) * wB;
            a3 += __uint_as_float(fB.y & 0xFFFF0000u) * wB;
            a4 += __uint_as_float(fB.z << 16) * wB;
            a5 += __uint_as_float(fB.z & 0xFFFF0000u) * wB;
            a6 += __uint_as_float(fB.w << 16) * wB;
            a7 += __uint_as_float(fB.w & 0xFFFF0000u) * wB;
        }
        if (i + 8 <= deg) {
            const int idx = i + q8;
            const int sA = sl[idx];
            const float wA = wl[idx * HEADS + h8];
            const uint4 fA = *(const uint4*)(fb + ((size_t)sA << 6) + (c8 << 3));
            a0 += __uint_as_float(fA.x << 16) * wA;
            a1 += __uint_as_float(fA.x & 0xFFFF0000u) * wA;
            a2 += __uint_as_float(fA.y << 16) * wA;
            a3 += __uint_as_float(fA.y & 0xFFFF0000u) * wA;
            a4 += __uint_as_float(fA.z << 16) * wA;
            a5 += __uint_as_float(fA.z & 0xFFFF0000u) * wA;
            a6 += __uint_as_float(fA.w << 16) * wA;
            a7 += __uint_as_float(fA.w & 0xFFFF0000u) * wA;
            i += 8;
        }
        if (i + q8 < deg) {                // tail (<8 edges), one guarded step
            const int idx = i + q8;
            const int sA = sl[idx];
            const float wA = wl[idx * HEADS + h8];
            const uint4 fA = *(const uint4*)(fb + ((size_t)sA << 6) + (c8 << 3));
            a0 += __uint_as_float(fA.x << 16) * wA;
            a1 += __uint_as_float(fA.x & 0xFFFF0000u) * wA;
            a2 += __uint_as_float(fA.y << 16) * wA;
            a3 += __uint_as_float(fA.y & 0xFFFF0000u) * wA;
            a4 += __uint_as_float(fA.z << 16) * wA;
            a5 += __uint_as_float(fA.z & 0xFFFF0000u) * wA;
            a6 += __uint_as_float(fA.w << 16) * wA;
            a7 += __uint_as_float(fA.w & 0xFFFF0000u) * wA;
        }
        // reduce over the 8 edge slots (lane bits 3..5)
        a0 += __shfl_xor(a0, 8, 64); a0 += __shfl_xor(a0, 16, 64); a0 += __shfl_xor(a0, 32, 64);
        a1 += __shfl_xor(a1, 8, 64); a1 += __shfl_xor(a1, 16, 64); a1 += __shfl_xor(a1, 32, 64);
        a2 += __shfl_xor(a2, 8, 64); a2 += __shfl_xor(a2, 16, 64); a2 += __shfl_xor(a2, 32, 64);
        a3 += __shfl_xor(a3, 8, 64); a3 += __shfl_xor(a3, 16, 64); a3 += __shfl_xor(a3, 32, 64);
        a4 += __shfl_xor(a4, 8, 64); a4 += __shfl_xor(a4, 16, 64); a4 += __shfl_xor(a4, 32, 64);
        a5 += __shfl_xor(a5, 8, 64); a5 += __shfl_xor(a5, 16, 64); a5 += __shfl_xor(a5, 32, 64);
        a6 += __shfl_xor(a6, 8, 64); a6 += __shfl_xor(a6, 16, 64); a6 += __shfl_xor(a6, 32, 64);
        a7 += __shfl_xor(a7, 8, 64); a7 += __shfl_xor(a7, 16, 64); a7 += __shfl_xor(a7, 32, 64);
        if (q8 == 0) {
            f32x4 v0 = {a0 * inv_z, a1 * inv_z, a2 * inv_z, a3 * inv_z};
            f32x4 v1 = {a4 * inv_z, a5 * inv_z, a6 * inv_z, a7 * inv_z};
            *(f32x4*)(rst + (size_t)n * HD + (c8 << 3))     = v0;
            *(f32x4*)(rst + (size_t)n * HD + (c8 << 3) + 4) = v1;
        }
    } else {
        // ---- rare big-degree path: two passes, recompute ----
        const int hA = lane & 3;
        const int eo = lane >> 2;
        const float er_nA = er[n * HEADS + hA];
        const float b0 = ee[hA], b1 = ee[HEADS + hA], b2 = ee[2 * HEADS + hA];
        float zacc = 0.f;
        for (int base = 0; base < deg; base += 16) {
            const int idx = base + eo;
            if (idx < deg) {
                const int2 v = sc_csr[p0 + idx];
                const int ty = v.y >> 21;
                float s = el[v.x * HEADS + hA] + er_nA + ((ty == 0) ? b0 : ((ty == 1) ? b1 : b2));
                s = s > 0.f ? s : NEG_SLOPE * s;
                zacc += __expf(s);
            }
        }
#pragma unroll
        for (int m = 4; m < 64; m <<= 1) zacc += __shfl_xor(zacc, m, 64);
        const int h = lane >> 4;
        const int d = lane & 15;
        // every lane holds z[lane&3]; z[h] lives at lane h
        const float inv_z = __frcp_rn(__shfl(zacc, h, 64));
        const float er_n = er[n * HEADS + h];
        const float g0 = ee[h], g1 = ee[HEADS + h], g2 = ee[2 * HEADS + h];
        float racc = 0.f;
        for (int i = 0; i < deg; ++i) {
            const int2 v = sc_csr[p0 + i];
            const int ty = v.y >> 21;
            float s = el[v.x * HEADS + h] + er_n + ((ty == 0) ? g0 : ((ty == 1) ? g1 : g2));
            s = s > 0.f ? s : NEG_SLOPE * s;
            const float a = __expf(s) * inv_z;
            racc += __bfloat162float(featb[(size_t)v.x * HD + lane]) * a;
            if (d == 0) a_out[((size_t)(v.y & 0x1FFFFF) << 2) + h] = a;
        }
        rst[(size_t)n * HD + lane] = racc;
    }
}

extern "C" void kernel_launch(void* const* d_in, const int* in_sizes, int n_in,
                              void* d_out, int out_size, void* d_ws, size_t ws_size,
                              hipStream_t stream)
{
    const float* x        = (const float*)d_in[0];
    const float* W        = (const float*)d_in[1];
    const float* W_e      = (const float*)d_in[2];
    const float* attn_l   = (const float*)d_in[3];
    const float* attn_r   = (const float*)d_in[4];
    const float* attn_e   = (const float*)d_in[5];
    const float* edge_emb = (const float*)d_in[6];
    const int* src   = (const int*)d_in[7];
    const int* dst   = (const int*)d_in[8];
    const int* etype = (const int*)d_in[9];

    float* out     = (float*)d_out;
    float* rst_out = out;                              // N*H*D
    float* a_out   = out + (size_t)N_NODES * HD;       // E*H

    char* w = (char*)d_ws;
    __hip_bfloat16* featb = (__hip_bfloat16*)w; w += (size_t)N_NODES * HD * 2;   // 12.8 MB
    float* el    = (float*)w;  w += (size_t)N_NODES * HEADS * 4;    //  1.6 MB
    float* er    = (float*)w;  w += (size_t)N_NODES * HEADS * 4;    //  1.6 MB
    float* ee    = (float*)w;  w += 64;
    int*   ptr   = (int*)w;    w += (size_t)(N_NODES + 8) * 4;      //  0.4 MB
    int*   deg   = (int*)w;    w += (size_t)(N_NODES + 8) * 4;      //  0.4 MB
    int*   cnt   = (int*)w;    w += (size_t)(NBUCK + 8) * 4;        //  3.2 KB
    short* WTb   = (short*)w;  w += (size_t)WTROWS * IN_FEATS * 2;  //   20 KB
    int2*  sc_bucket = (int2*)w; w += ((size_t)NBUCK * BCAP + 2048) * 8;  // 16.4 MB
    // total ~33.3 MB

    // 1) WTb[80][128] (feat + el/er columns) + zero(cnt)
    wt_prep_kernel<<<(WTROWS * IN_FEATS) / 256, 256, 0, stream>>>(
        W, attn_l, attn_r, WTb, cnt);

    // 2) FUSED: scatter (0..399) || ee (400) || feat GEMM w/ el-er tile (401..)
    feat_scatter_kernel<<<PBLK + 1 + NFEAT, 320, 0, stream>>>(
        x, WTb, edge_emb, W_e, attn_e,
        src, dst, etype, featb, el, er, ee, cnt, sc_bucket);

    // 3) CSR finalize in-place
    bucket_csr_kernel<<<NBUCK, 256, 0, stream>>>(sc_bucket, cnt, ptr, deg);

    // 4) aggregation + fused a_out
    agg_kernel<<<N_NODES / 4, 256, 0, stream>>>(
        sc_bucket, ptr, deg, el, er, ee, featb, rst_out, a_out);
}